// Round 24
// baseline (234.204 us; speedup 1.0000x reference)
//
#include <hip/hip_runtime.h>

#define NNODES 50000
#define NEDGES 600000
#define DH 128
#define SCAN_THREADS 512
#define SCAN_ELEMS 2048
#define SCAN_BLOCKS ((NNODES + SCAN_ELEMS - 1) / SCAN_ELEMS)   // 25
#define WCONV_BLOCKS ((3 * DH * DH) / 256)                     // 192
#define NSLICES 32
#define NCHUNKS 8
#define CHUNK (NNODES / NCHUNKS)          // 6250
#define ESLICE (NEDGES / NSLICES)         // 18750
#define CNT_THREADS 1024

typedef __attribute__((ext_vector_type(4))) float f32x4;
typedef __attribute__((ext_vector_type(4))) _Float16 half4;
typedef __attribute__((ext_vector_type(8))) _Float16 half8;

// ---------------- chunked LDS-histogram degree count (no global atomics) ----------------
__global__ __launch_bounds__(CNT_THREADS) void count_chunked(
        const int* __restrict__ src, const int* __restrict__ dst,
        int* __restrict__ partIn, int* __restrict__ partOut) {
    __shared__ int hin[CHUNK];
    __shared__ int hout[CHUNK];
    int slice = blockIdx.x >> 3;          // 0..31
    int chunk = blockIdx.x & 7;           // 0..7
    int cbase = chunk * CHUNK;
    int t = threadIdx.x;
    for (int i = t; i < CHUNK; i += CNT_THREADS) { hin[i] = 0; hout[i] = 0; }
    __syncthreads();
    int e0 = slice * ESLICE;
    int e1 = e0 + ESLICE;
    for (int e = e0 + t; e < e1; e += CNT_THREADS) {
        int d = dst[e];
        unsigned dd = (unsigned)(d - cbase);
        if (dd < CHUNK) atomicAdd(&hin[dd], 1);
        int s = src[e];
        unsigned ss = (unsigned)(s - cbase);
        if (ss < CHUNK) atomicAdd(&hout[ss], 1);
    }
    __syncthreads();
    int* pi = partIn  + slice * NNODES + cbase;
    int* po = partOut + slice * NNODES + cbase;
    for (int i = t; i < CHUNK; i += CNT_THREADS) { pi[i] = hin[i]; po[i] = hout[i]; }
}

// ---------------- reduce partials -> cnt_in / cnt_out ----------------
__global__ void reduce_counts(const int* __restrict__ partIn, const int* __restrict__ partOut,
                              int* __restrict__ cnt_in, int* __restrict__ cnt_out, int N) {
    int n = blockIdx.x * blockDim.x + threadIdx.x;
    if (n >= N) return;
    int ti = 0, to = 0;
#pragma unroll
    for (int s = 0; s < NSLICES; ++s) {
        ti += partIn[s * NNODES + n];
        to += partOut[s * NNODES + n];
    }
    cnt_in[n] = ti;
    cnt_out[n] = to;
}

// ---------------- multi-block scan, phase 1: per-block sums ----------------
__global__ __launch_bounds__(SCAN_THREADS) void scan_sums(
        const int* __restrict__ counts, int* __restrict__ bsums, int N) {
    __shared__ int red[SCAN_THREADS / 64];
    int b = blockIdx.x, t = threadIdx.x;
    int base = b * SCAN_ELEMS + t * 4;
    int s = 0;
    if (base + 3 < N) {
        int4 v = *(const int4*)(counts + base);
        s = v.x + v.y + v.z + v.w;
    } else {
        for (int j = 0; j < 4; ++j) if (base + j < N) s += counts[base + j];
    }
#pragma unroll
    for (int off = 32; off > 0; off >>= 1) s += __shfl_down(s, off);
    if ((t & 63) == 0) red[t >> 6] = s;
    __syncthreads();
    if (t == 0) {
        int tot = 0;
#pragma unroll
        for (int w = 0; w < SCAN_THREADS / 64; ++w) tot += red[w];
        bsums[b] = tot;
    }
}

// ---------------- scan phase 2 + norms + cursor init (fused) ----------------
__global__ __launch_bounds__(SCAN_THREADS) void scan_final(
        const int* __restrict__ counts, const int* __restrict__ bsums,
        const int* __restrict__ cnt_out, int* __restrict__ off,
        int* __restrict__ cursor, float* __restrict__ out_inv,
        float* __restrict__ in_inv, int N, int nb) {
    __shared__ int lds[SCAN_THREADS];
    __shared__ int base_s;
    int b = blockIdx.x, t = threadIdx.x;
    if (t == 0) {
        int acc = 0;
        for (int i = 0; i < b; ++i) acc += bsums[i];
        base_s = acc;
    }
    int i0 = b * SCAN_ELEMS + t * 4;
    int v[4]; int s = 0;
#pragma unroll
    for (int j = 0; j < 4; ++j) {
        int idx = i0 + j;
        v[j] = (idx < N) ? counts[idx] : 0;
        s += v[j];
    }
    lds[t] = s;
    __syncthreads();
    for (int d = 1; d < SCAN_THREADS; d <<= 1) {
        int x = lds[t];
        int y = (t >= d) ? lds[t - d] : 0;
        __syncthreads();
        lds[t] = x + y;
        __syncthreads();
    }
    int excl = (t == 0) ? 0 : lds[t - 1];
    int run = base_s + excl;
#pragma unroll
    for (int j = 0; j < 4; ++j) {
        int idx = i0 + j;
        if (idx < N) {
            off[idx]    = run;
            cursor[idx] = run;
            in_inv[idx]  = rsqrtf(fmaxf((float)v[j], 1.0f));
            out_inv[idx] = rsqrtf(fmaxf((float)cnt_out[idx], 1.0f));
        }
        run += v[j];
    }
    if (b == nb - 1 && t == SCAN_THREADS - 1) off[N] = run;
}

// ---------------- scatter edges into dst-CSR (cursor atomics, proven) ----------------
__global__ void scatter_kernel(const int* __restrict__ src, const int* __restrict__ dst,
                               int* __restrict__ cursor, int* __restrict__ csr_src, int E) {
    int i = blockIdx.x * blockDim.x + threadIdx.x;
    if (i < E) {
        int pos = atomicAdd(&cursor[dst[i]], 1);
        csr_src[pos] = src[i];
    }
}

// ---------------- prep: W -> transposed split-fp16 hi/lo + features fp32 -> fp16*out_inv ----------------
__global__ void prep_kernel(const float* __restrict__ W0, const float* __restrict__ W1,
                            const float* __restrict__ W2,
                            _Float16* __restrict__ WThi, _Float16* __restrict__ WTlo,
                            const float* __restrict__ fin, const float* __restrict__ out_inv,
                            _Float16* __restrict__ fout, int n4) {
    if (blockIdx.x < WCONV_BLOCKS) {
        int t = blockIdx.x * blockDim.x + threadIdx.x;   // < 3*DH*DH
        int L = t >> 14;
        int idx = t & (DH * DH - 1);
        int n = idx >> 7;
        int k = idx & 127;
        const float* W = (L == 0) ? W0 : ((L == 1) ? W1 : W2);
        float w = W[k * DH + n];
        _Float16 hi = (_Float16)w;
        _Float16 lo = (_Float16)(w - (float)hi);
        WThi[t] = hi;              // t = L*16384 + n*128 + k
        WTlo[t] = lo;
    } else {
        int i = (blockIdx.x - WCONV_BLOCKS) * blockDim.x + threadIdx.x;
        if (i < n4) {
            float sc = out_inv[i >> 5];          // row = i*4/128
            float4 v = ((const float4*)fin)[i];
            half4 h = {(_Float16)(v.x * sc), (_Float16)(v.y * sc),
                       (_Float16)(v.z * sc), (_Float16)(v.w * sc)};
            ((half4*)fout)[i] = h;
        }
    }
}

// ---------------- SpMM (gather pre-scaled fp16), half-wave per dst row, unroll x4 ----------------
// X[d] = in_inv[d] * sum_{s in N(d)} h'[s]    (h' already has out_inv folded in)
__global__ __launch_bounds__(256) void spmm_csr(
        const _Float16* __restrict__ h, const int* __restrict__ row_off,
        const int* __restrict__ csr_src,
        const float* __restrict__ in_inv, _Float16* __restrict__ X, int N) {
    int gw   = (blockIdx.x * blockDim.x + threadIdx.x) >> 6;
    int lane = threadIdx.x & 63;
    int half = lane >> 5;          // two rows per wave
    int l5   = lane & 31;          // 32 lanes x 8B = 256B row
    int row  = gw * 2 + half;
    if (row >= N) return;
    int start = row_off[row], end = row_off[row + 1];
    float4 acc0 = make_float4(0.f, 0.f, 0.f, 0.f);
    float4 acc1 = make_float4(0.f, 0.f, 0.f, 0.f);
    int e = start;
    for (; e + 4 <= end; e += 4) {
        int s0 = csr_src[e];
        int s1 = csr_src[e + 1];
        int s2 = csr_src[e + 2];
        int s3 = csr_src[e + 3];
        half4 v0 = ((const half4*)(h + (size_t)s0 * DH))[l5];
        half4 v1 = ((const half4*)(h + (size_t)s1 * DH))[l5];
        half4 v2 = ((const half4*)(h + (size_t)s2 * DH))[l5];
        half4 v3 = ((const half4*)(h + (size_t)s3 * DH))[l5];
        acc0.x += (float)v0.x; acc0.y += (float)v0.y;
        acc0.z += (float)v0.z; acc0.w += (float)v0.w;
        acc1.x += (float)v1.x; acc1.y += (float)v1.y;
        acc1.z += (float)v1.z; acc1.w += (float)v1.w;
        acc0.x += (float)v2.x; acc0.y += (float)v2.y;
        acc0.z += (float)v2.z; acc0.w += (float)v2.w;
        acc1.x += (float)v3.x; acc1.y += (float)v3.y;
        acc1.z += (float)v3.z; acc1.w += (float)v3.w;
    }
    for (; e < end; ++e) {
        int s0 = csr_src[e];
        half4 v0 = ((const half4*)(h + (size_t)s0 * DH))[l5];
        acc0.x += (float)v0.x; acc0.y += (float)v0.y;
        acc0.z += (float)v0.z; acc0.w += (float)v0.w;
    }
    float ii = in_inv[row];
    half4 o;
    o.x = (_Float16)((acc0.x + acc1.x) * ii);
    o.y = (_Float16)((acc0.y + acc1.y) * ii);
    o.z = (_Float16)((acc0.z + acc1.z) * ii);
    o.w = (_Float16)((acc0.w + acc1.w) * ii);
    ((half4*)(X + (size_t)row * DH))[l5] = o;
}

// ---------------- MFMA GEMM (fp16 A, split-fp16 W, 2-pass): Y = relu(X @ W + b) * out_inv ----------------
template<int RELU>
__global__ __launch_bounds__(256, 2) void gemm_mfma(
        const _Float16* __restrict__ X,
        const _Float16* __restrict__ WThi, const _Float16* __restrict__ WTlo,
        const float* __restrict__ bias, const float* __restrict__ out_inv,
        _Float16* __restrict__ Y, int Mtiles) {
    int lane  = threadIdx.x & 63;
    int gwave = (blockIdx.x * blockDim.x + threadIdx.x) >> 6;
    int nwav  = (gridDim.x * blockDim.x) >> 6;
    int nhalf = gwave & 1;          // col half: 0 -> 0..63, 1 -> 64..127
    int wstart  = gwave >> 1;
    int wstride = nwav >> 1;

    int r  = lane & 15;             // A-row / B-col / D-col within tile
    int kq = lane >> 4;             // k quarter within a K=32 fragment

    // persistent B fragments: [hi/lo][ntile][kfrag]
    half8 B[2][4][4];
#pragma unroll
    for (int nt = 0; nt < 4; ++nt) {
        int n = 64 * nhalf + 16 * nt + r;
#pragma unroll
        for (int kf = 0; kf < 4; ++kf) {
            B[0][nt][kf] = *(const half8*)(WThi + n * DH + 32 * kf + 8 * kq);
            B[1][nt][kf] = *(const half8*)(WTlo + n * DH + 32 * kf + 8 * kq);
        }
    }
    float bs[4];
#pragma unroll
    for (int nt = 0; nt < 4; ++nt) bs[nt] = bias[64 * nhalf + 16 * nt + r];

    for (int mt = wstart; mt < Mtiles; mt += wstride) {
        int m0 = mt * 16;
        const _Float16* xp = X + (size_t)(m0 + r) * DH + 8 * kq;
        half8 A[4];
#pragma unroll
        for (int kf = 0; kf < 4; ++kf)
            A[kf] = *(const half8*)(xp + 32 * kf);
        f32x4 acc[4];
#pragma unroll
        for (int nt = 0; nt < 4; ++nt)
            acc[nt] = (f32x4){bs[nt], bs[nt], bs[nt], bs[nt]};
#pragma unroll
        for (int kf = 0; kf < 4; ++kf) {
#pragma unroll
            for (int nt = 0; nt < 4; ++nt) {
                acc[nt] = __builtin_amdgcn_mfma_f32_16x16x32_f16(A[kf], B[0][nt][kf], acc[nt], 0, 0, 0);
                acc[nt] = __builtin_amdgcn_mfma_f32_16x16x32_f16(A[kf], B[1][nt][kf], acc[nt], 0, 0, 0);
            }
        }
        // D: row = m0 + 4*kq + j, col = 64*nhalf + 16*nt + r
        float sc[4];
#pragma unroll
        for (int j = 0; j < 4; ++j) sc[j] = out_inv[m0 + 4 * kq + j];
#pragma unroll
        for (int nt = 0; nt < 4; ++nt) {
            int n = 64 * nhalf + 16 * nt + r;
            _Float16* yp = Y + (size_t)(m0 + 4 * kq) * DH + n;
#pragma unroll
            for (int j = 0; j < 4; ++j) {
                float v = acc[nt][j];
                if (RELU) v = fmaxf(v, 0.f);
                yp[(size_t)j * DH] = (_Float16)(v * sc[j]);
            }
        }
    }
}

// ---------------- layer-3 projection: one row per lane (input pre-scaled by out_inv) ----------------
__global__ __launch_bounds__(256) void proj_out(
        const _Float16* __restrict__ X,
        const float* __restrict__ W, float* __restrict__ Z, int N) {
    __shared__ float Wl[DH * 10];
    for (int i = threadIdx.x; i < DH * 10; i += blockDim.x) Wl[i] = W[i];
    __syncthreads();

    int row = blockIdx.x * blockDim.x + threadIdx.x;
    if (row >= N) return;

    float acc[10];
#pragma unroll
    for (int o = 0; o < 10; ++o) acc[o] = 0.f;

    const half8* xp = (const half8*)(X + (size_t)row * DH);
#pragma unroll
    for (int q = 0; q < 16; ++q) {       // 16 x 8 fp16 = 128
        half8 v = xp[q];
#pragma unroll
        for (int j = 0; j < 8; ++j) {
            float x = (float)v[j];
            const float* wp = Wl + (q * 8 + j) * 10;
#pragma unroll
            for (int o = 0; o < 10; ++o)
                acc[o] += x * wp[o];
        }
    }
    float* zp = Z + (size_t)row * 10;
#pragma unroll
    for (int o = 0; o < 10; ++o) zp[o] = acc[o];
}

// ---------------- layer-3 aggregation: out[d] = in_inv[d]*sum Z[s] + b3 ----------------
__global__ void agg10(const float* __restrict__ Z, const int* __restrict__ row_off,
                      const int* __restrict__ csr_src, const float* __restrict__ in_inv,
                      const float* __restrict__ b, float* __restrict__ out, int N) {
    int r = blockIdx.x * blockDim.x + threadIdx.x;
    if (r >= N) return;
    float2 acc[5] = {};
    int start = row_off[r], end = row_off[r + 1];
    for (int e = start; e < end; ++e) {
        int s = csr_src[e];
        const float2* zp = (const float2*)(Z + (size_t)s * 10);
#pragma unroll
        for (int o = 0; o < 5; ++o) {
            float2 z = zp[o];
            acc[o].x += z.x; acc[o].y += z.y;
        }
    }
    float ii = in_inv[r];
#pragma unroll
    for (int o = 0; o < 5; ++o) {
        out[(size_t)r * 10 + 2 * o]     = acc[o].x * ii + b[2 * o];
        out[(size_t)r * 10 + 2 * o + 1] = acc[o].y * ii + b[2 * o + 1];
    }
}

extern "C" void kernel_launch(void* const* d_in, const int* in_sizes, int n_in,
                              void* d_out, int out_size, void* d_ws, size_t ws_size,
                              hipStream_t stream) {
    const float* features = (const float*)d_in[0];
    const int*   src      = (const int*)d_in[1];
    const int*   dst      = (const int*)d_in[2];
    const float* W0 = (const float*)d_in[3];
    const float* b0 = (const float*)d_in[4];
    const float* W1 = (const float*)d_in[5];
    const float* b1 = (const float*)d_in[6];
    const float* W2 = (const float*)d_in[7];
    const float* b2 = (const float*)d_in[8];
    const float* W3 = (const float*)d_in[9];
    const float* b3 = (const float*)d_in[10];
    float* out = (float*)d_out;

    char* ws = (char*)d_ws;
    int*   cnt_out = (int*)ws;                       // N
    int*   cnt_in  = cnt_out + NNODES;               // N
    int*   cursor  = cnt_in + NNODES;                // N
    int*   row_off = cursor + NNODES;                // N+1
    int*   bsums   = row_off + NNODES + 1;           // SCAN_BLOCKS
    float* out_inv = (float*)(bsums + SCAN_BLOCKS);  // N
    float* in_inv  = out_inv + NNODES;               // N
    int*   csr_src = (int*)(in_inv + NNODES);        // E
    size_t metaInts = (size_t)(6 * NNODES + 1 + SCAN_BLOCKS) + NEDGES;
    size_t off = ((metaInts * 4 + 255) / 256) * 256;
    _Float16* WThi = (_Float16*)(ws + off);  off += 3 * DH * DH * sizeof(_Float16);
    _Float16* WTlo = (_Float16*)(ws + off);  off += 3 * DH * DH * sizeof(_Float16);
    off = ((off + 255) / 256) * 256;
    _Float16* X16 = (_Float16*)(ws + off); off += (size_t)NNODES * DH * sizeof(_Float16);
    _Float16* Y16 = (_Float16*)(ws + off); off += (size_t)NNODES * DH * sizeof(_Float16);
    _Float16* F16 = (_Float16*)(ws + off); off += (size_t)NNODES * DH * sizeof(_Float16);
    float*  Z   = (float*)X16;             // layer-3: X16 dead after layer-2 gemm
    // partial count arrays alias X16/Y16 (dead until layer-0 spmm/gemm, stream-ordered)
    int* partIn  = (int*)X16;              // NSLICES*N ints = 6.4MB <= 12.8MB
    int* partOut = (int*)Y16;

    const int n4 = NNODES * DH / 4;

    // ---- CSR build + norms + W conversion + feature fp16 (once per call) ----
    count_chunked<<<NSLICES * NCHUNKS, CNT_THREADS, 0, stream>>>(src, dst, partIn, partOut);
    reduce_counts<<<(NNODES + 255) / 256, 256, 0, stream>>>(partIn, partOut, cnt_in, cnt_out, NNODES);
    scan_sums<<<SCAN_BLOCKS, SCAN_THREADS, 0, stream>>>(cnt_in, bsums, NNODES);
    scan_final<<<SCAN_BLOCKS, SCAN_THREADS, 0, stream>>>(cnt_in, bsums, cnt_out, row_off,
                                                         cursor, out_inv, in_inv, NNODES, SCAN_BLOCKS);
    scatter_kernel<<<(NEDGES + 255) / 256, 256, 0, stream>>>(src, dst, cursor, csr_src, NEDGES);
    prep_kernel<<<WCONV_BLOCKS + (n4 + 255) / 256, 256, 0, stream>>>(W0, W1, W2, WThi, WTlo,
                                                                     features, out_inv, F16, n4);

    const int spmm_blocks = (NNODES / 2 + 3) / 4;
    const int Mtiles = NNODES / 16;                 // 3125
    const int gemm_blocks = 512;

    // Layer 0
    spmm_csr<<<spmm_blocks, 256, 0, stream>>>(F16, row_off, csr_src, in_inv, X16, NNODES);
    gemm_mfma<1><<<gemm_blocks, 256, 0, stream>>>(X16, WThi, WTlo, b0, out_inv, Y16, Mtiles);
    // Layer 1
    spmm_csr<<<spmm_blocks, 256, 0, stream>>>(Y16, row_off, csr_src, in_inv, X16, NNODES);
    gemm_mfma<1><<<gemm_blocks, 256, 0, stream>>>(X16, WThi + DH * DH, WTlo + DH * DH, b1, out_inv, Y16, Mtiles);
    // Layer 2
    spmm_csr<<<spmm_blocks, 256, 0, stream>>>(Y16, row_off, csr_src, in_inv, X16, NNODES);
    gemm_mfma<1><<<gemm_blocks, 256, 0, stream>>>(X16, WThi + 2 * DH * DH, WTlo + 2 * DH * DH, b2, out_inv, Y16, Mtiles);
    // Layer 3: project to O=10 first (input pre-scaled), then aggregate 10-wide
    proj_out<<<(NNODES + 255) / 256, 256, 0, stream>>>(Y16, W3, Z, NNODES);
    agg10<<<(NNODES + 255) / 256, 256, 0, stream>>>(Z, row_off, csr_src, in_inv, b3, out, NNODES);
}

// Round 25
// 229.703 us; speedup vs baseline: 1.0196x; 1.0196x over previous
//
#include <hip/hip_runtime.h>

#define NNODES 50000
#define NEDGES 600000
#define DH 128
#define SCAN_THREADS 512
#define SCAN_ELEMS 2048
#define SCAN_BLOCKS ((NNODES + SCAN_ELEMS - 1) / SCAN_ELEMS)   // 25
#define WCONV_BLOCKS ((3 * DH * DH) / 256)                     // 192
#define NSLICES 32
#define NCHUNKS 8
#define CHUNK (NNODES / NCHUNKS)          // 6250
#define ESLICE (NEDGES / NSLICES)         // 18750
#define CNT_THREADS 1024

typedef __attribute__((ext_vector_type(4))) float f32x4;
typedef __attribute__((ext_vector_type(4))) _Float16 half4;
typedef __attribute__((ext_vector_type(8))) _Float16 half8;

// ---------------- chunked LDS-histogram degree count (no global atomics) ----------------
__global__ __launch_bounds__(CNT_THREADS) void count_chunked(
        const int* __restrict__ src, const int* __restrict__ dst,
        int* __restrict__ partIn, int* __restrict__ partOut) {
    __shared__ int hin[CHUNK];
    __shared__ int hout[CHUNK];
    int slice = blockIdx.x >> 3;          // 0..31
    int chunk = blockIdx.x & 7;           // 0..7
    int cbase = chunk * CHUNK;
    int t = threadIdx.x;
    for (int i = t; i < CHUNK; i += CNT_THREADS) { hin[i] = 0; hout[i] = 0; }
    __syncthreads();
    int e0 = slice * ESLICE;
    int e1 = e0 + ESLICE;
    for (int e = e0 + t; e < e1; e += CNT_THREADS) {
        int d = dst[e];
        unsigned dd = (unsigned)(d - cbase);
        if (dd < CHUNK) atomicAdd(&hin[dd], 1);
        int s = src[e];
        unsigned ss = (unsigned)(s - cbase);
        if (ss < CHUNK) atomicAdd(&hout[ss], 1);
    }
    __syncthreads();
    int* pi = partIn  + slice * NNODES + cbase;
    int* po = partOut + slice * NNODES + cbase;
    for (int i = t; i < CHUNK; i += CNT_THREADS) { pi[i] = hin[i]; po[i] = hout[i]; }
}

// ---------------- reduce partials -> cnt_in / cnt_out ----------------
__global__ void reduce_counts(const int* __restrict__ partIn, const int* __restrict__ partOut,
                              int* __restrict__ cnt_in, int* __restrict__ cnt_out, int N) {
    int n = blockIdx.x * blockDim.x + threadIdx.x;
    if (n >= N) return;
    int ti = 0, to = 0;
#pragma unroll
    for (int s = 0; s < NSLICES; ++s) {
        ti += partIn[s * NNODES + n];
        to += partOut[s * NNODES + n];
    }
    cnt_in[n] = ti;
    cnt_out[n] = to;
}

// ---------------- multi-block scan, phase 1: per-block sums ----------------
__global__ __launch_bounds__(SCAN_THREADS) void scan_sums(
        const int* __restrict__ counts, int* __restrict__ bsums, int N) {
    __shared__ int red[SCAN_THREADS / 64];
    int b = blockIdx.x, t = threadIdx.x;
    int base = b * SCAN_ELEMS + t * 4;
    int s = 0;
    if (base + 3 < N) {
        int4 v = *(const int4*)(counts + base);
        s = v.x + v.y + v.z + v.w;
    } else {
        for (int j = 0; j < 4; ++j) if (base + j < N) s += counts[base + j];
    }
#pragma unroll
    for (int off = 32; off > 0; off >>= 1) s += __shfl_down(s, off);
    if ((t & 63) == 0) red[t >> 6] = s;
    __syncthreads();
    if (t == 0) {
        int tot = 0;
#pragma unroll
        for (int w = 0; w < SCAN_THREADS / 64; ++w) tot += red[w];
        bsums[b] = tot;
    }
}

// ---------------- scan phase 2 + norms + cursor init (fused) ----------------
__global__ __launch_bounds__(SCAN_THREADS) void scan_final(
        const int* __restrict__ counts, const int* __restrict__ bsums,
        const int* __restrict__ cnt_out, int* __restrict__ off,
        int* __restrict__ cursor, float* __restrict__ out_inv,
        float* __restrict__ in_inv, int N, int nb) {
    __shared__ int lds[SCAN_THREADS];
    __shared__ int base_s;
    int b = blockIdx.x, t = threadIdx.x;
    if (t == 0) {
        int acc = 0;
        for (int i = 0; i < b; ++i) acc += bsums[i];
        base_s = acc;
    }
    int i0 = b * SCAN_ELEMS + t * 4;
    int v[4]; int s = 0;
#pragma unroll
    for (int j = 0; j < 4; ++j) {
        int idx = i0 + j;
        v[j] = (idx < N) ? counts[idx] : 0;
        s += v[j];
    }
    lds[t] = s;
    __syncthreads();
    for (int d = 1; d < SCAN_THREADS; d <<= 1) {
        int x = lds[t];
        int y = (t >= d) ? lds[t - d] : 0;
        __syncthreads();
        lds[t] = x + y;
        __syncthreads();
    }
    int excl = (t == 0) ? 0 : lds[t - 1];
    int run = base_s + excl;
#pragma unroll
    for (int j = 0; j < 4; ++j) {
        int idx = i0 + j;
        if (idx < N) {
            off[idx]    = run;
            cursor[idx] = run;
            in_inv[idx]  = rsqrtf(fmaxf((float)v[j], 1.0f));
            out_inv[idx] = rsqrtf(fmaxf((float)cnt_out[idx], 1.0f));
        }
        run += v[j];
    }
    if (b == nb - 1 && t == SCAN_THREADS - 1) off[N] = run;
}

// ---------------- scatter edges into dst-CSR (cursor atomics, proven) ----------------
__global__ void scatter_kernel(const int* __restrict__ src, const int* __restrict__ dst,
                               int* __restrict__ cursor, int* __restrict__ csr_src, int E) {
    int i = blockIdx.x * blockDim.x + threadIdx.x;
    if (i < E) {
        int pos = atomicAdd(&cursor[dst[i]], 1);
        csr_src[pos] = src[i];
    }
}

// ---------------- prep: W -> transposed split-fp16 hi/lo + features fp32 -> fp16*out_inv ----------------
__global__ void prep_kernel(const float* __restrict__ W0, const float* __restrict__ W1,
                            const float* __restrict__ W2,
                            _Float16* __restrict__ WThi, _Float16* __restrict__ WTlo,
                            const float* __restrict__ fin, const float* __restrict__ out_inv,
                            _Float16* __restrict__ fout, int n4) {
    if (blockIdx.x < WCONV_BLOCKS) {
        int t = blockIdx.x * blockDim.x + threadIdx.x;   // < 3*DH*DH
        int L = t >> 14;
        int idx = t & (DH * DH - 1);
        int n = idx >> 7;
        int k = idx & 127;
        const float* W = (L == 0) ? W0 : ((L == 1) ? W1 : W2);
        float w = W[k * DH + n];
        _Float16 hi = (_Float16)w;
        _Float16 lo = (_Float16)(w - (float)hi);
        WThi[t] = hi;              // t = L*16384 + n*128 + k
        WTlo[t] = lo;
    } else {
        int i = (blockIdx.x - WCONV_BLOCKS) * blockDim.x + threadIdx.x;
        if (i < n4) {
            float sc = out_inv[i >> 5];          // row = i*4/128
            float4 v = ((const float4*)fin)[i];
            half4 h = {(_Float16)(v.x * sc), (_Float16)(v.y * sc),
                       (_Float16)(v.z * sc), (_Float16)(v.w * sc)};
            ((half4*)fout)[i] = h;
        }
    }
}

// ---------------- SpMM (gather pre-scaled fp16), half-wave per dst row, unroll x8 ----------------
// X[d] = in_inv[d] * sum_{s in N(d)} h'[s]    (h' already has out_inv folded in)
__global__ __launch_bounds__(256) void spmm_csr(
        const _Float16* __restrict__ h, const int* __restrict__ row_off,
        const int* __restrict__ csr_src,
        const float* __restrict__ in_inv, _Float16* __restrict__ X, int N) {
    int gw   = (blockIdx.x * blockDim.x + threadIdx.x) >> 6;
    int lane = threadIdx.x & 63;
    int half = lane >> 5;          // two rows per wave
    int l5   = lane & 31;          // 32 lanes x 8B = 256B row
    int row  = gw * 2 + half;
    if (row >= N) return;
    int start = row_off[row], end = row_off[row + 1];
    float4 acc0 = make_float4(0.f, 0.f, 0.f, 0.f);
    float4 acc1 = make_float4(0.f, 0.f, 0.f, 0.f);
    int e = start;
    for (; e + 8 <= end; e += 8) {
        int s0 = csr_src[e];
        int s1 = csr_src[e + 1];
        int s2 = csr_src[e + 2];
        int s3 = csr_src[e + 3];
        int s4 = csr_src[e + 4];
        int s5 = csr_src[e + 5];
        int s6 = csr_src[e + 6];
        int s7 = csr_src[e + 7];
        half4 v0 = ((const half4*)(h + (size_t)s0 * DH))[l5];
        half4 v1 = ((const half4*)(h + (size_t)s1 * DH))[l5];
        half4 v2 = ((const half4*)(h + (size_t)s2 * DH))[l5];
        half4 v3 = ((const half4*)(h + (size_t)s3 * DH))[l5];
        half4 v4 = ((const half4*)(h + (size_t)s4 * DH))[l5];
        half4 v5 = ((const half4*)(h + (size_t)s5 * DH))[l5];
        half4 v6 = ((const half4*)(h + (size_t)s6 * DH))[l5];
        half4 v7 = ((const half4*)(h + (size_t)s7 * DH))[l5];
        acc0.x += (float)v0.x; acc0.y += (float)v0.y; acc0.z += (float)v0.z; acc0.w += (float)v0.w;
        acc1.x += (float)v1.x; acc1.y += (float)v1.y; acc1.z += (float)v1.z; acc1.w += (float)v1.w;
        acc0.x += (float)v2.x; acc0.y += (float)v2.y; acc0.z += (float)v2.z; acc0.w += (float)v2.w;
        acc1.x += (float)v3.x; acc1.y += (float)v3.y; acc1.z += (float)v3.z; acc1.w += (float)v3.w;
        acc0.x += (float)v4.x; acc0.y += (float)v4.y; acc0.z += (float)v4.z; acc0.w += (float)v4.w;
        acc1.x += (float)v5.x; acc1.y += (float)v5.y; acc1.z += (float)v5.z; acc1.w += (float)v5.w;
        acc0.x += (float)v6.x; acc0.y += (float)v6.y; acc0.z += (float)v6.z; acc0.w += (float)v6.w;
        acc1.x += (float)v7.x; acc1.y += (float)v7.y; acc1.z += (float)v7.z; acc1.w += (float)v7.w;
    }
    for (; e + 2 <= end; e += 2) {
        int s0 = csr_src[e];
        int s1 = csr_src[e + 1];
        half4 v0 = ((const half4*)(h + (size_t)s0 * DH))[l5];
        half4 v1 = ((const half4*)(h + (size_t)s1 * DH))[l5];
        acc0.x += (float)v0.x; acc0.y += (float)v0.y; acc0.z += (float)v0.z; acc0.w += (float)v0.w;
        acc1.x += (float)v1.x; acc1.y += (float)v1.y; acc1.z += (float)v1.z; acc1.w += (float)v1.w;
    }
    if (e < end) {
        int s0 = csr_src[e];
        half4 v0 = ((const half4*)(h + (size_t)s0 * DH))[l5];
        acc0.x += (float)v0.x; acc0.y += (float)v0.y; acc0.z += (float)v0.z; acc0.w += (float)v0.w;
    }
    float ii = in_inv[row];
    half4 o;
    o.x = (_Float16)((acc0.x + acc1.x) * ii);
    o.y = (_Float16)((acc0.y + acc1.y) * ii);
    o.z = (_Float16)((acc0.z + acc1.z) * ii);
    o.w = (_Float16)((acc0.w + acc1.w) * ii);
    ((half4*)(X + (size_t)row * DH))[l5] = o;
}

// ---------------- MFMA GEMM (fp16 A, split-fp16 W, 2-pass): Y = relu(X @ W + b) * out_inv ----------------
template<int RELU>
__global__ __launch_bounds__(256, 2) void gemm_mfma(
        const _Float16* __restrict__ X,
        const _Float16* __restrict__ WThi, const _Float16* __restrict__ WTlo,
        const float* __restrict__ bias, const float* __restrict__ out_inv,
        _Float16* __restrict__ Y, int Mtiles) {
    int lane  = threadIdx.x & 63;
    int gwave = (blockIdx.x * blockDim.x + threadIdx.x) >> 6;
    int nwav  = (gridDim.x * blockDim.x) >> 6;
    int nhalf = gwave & 1;          // col half: 0 -> 0..63, 1 -> 64..127
    int wstart  = gwave >> 1;
    int wstride = nwav >> 1;

    int r  = lane & 15;             // A-row / B-col / D-col within tile
    int kq = lane >> 4;             // k quarter within a K=32 fragment

    // persistent B fragments: [hi/lo][ntile][kfrag]
    half8 B[2][4][4];
#pragma unroll
    for (int nt = 0; nt < 4; ++nt) {
        int n = 64 * nhalf + 16 * nt + r;
#pragma unroll
        for (int kf = 0; kf < 4; ++kf) {
            B[0][nt][kf] = *(const half8*)(WThi + n * DH + 32 * kf + 8 * kq);
            B[1][nt][kf] = *(const half8*)(WTlo + n * DH + 32 * kf + 8 * kq);
        }
    }
    float bs[4];
#pragma unroll
    for (int nt = 0; nt < 4; ++nt) bs[nt] = bias[64 * nhalf + 16 * nt + r];

    for (int mt = wstart; mt < Mtiles; mt += wstride) {
        int m0 = mt * 16;
        const _Float16* xp = X + (size_t)(m0 + r) * DH + 8 * kq;
        half8 A[4];
#pragma unroll
        for (int kf = 0; kf < 4; ++kf)
            A[kf] = *(const half8*)(xp + 32 * kf);
        f32x4 acc[4];
#pragma unroll
        for (int nt = 0; nt < 4; ++nt)
            acc[nt] = (f32x4){bs[nt], bs[nt], bs[nt], bs[nt]};
#pragma unroll
        for (int kf = 0; kf < 4; ++kf) {
#pragma unroll
            for (int nt = 0; nt < 4; ++nt) {
                acc[nt] = __builtin_amdgcn_mfma_f32_16x16x32_f16(A[kf], B[0][nt][kf], acc[nt], 0, 0, 0);
                acc[nt] = __builtin_amdgcn_mfma_f32_16x16x32_f16(A[kf], B[1][nt][kf], acc[nt], 0, 0, 0);
            }
        }
        // D: row = m0 + 4*kq + j, col = 64*nhalf + 16*nt + r
        float sc[4];
#pragma unroll
        for (int j = 0; j < 4; ++j) sc[j] = out_inv[m0 + 4 * kq + j];
#pragma unroll
        for (int nt = 0; nt < 4; ++nt) {
            int n = 64 * nhalf + 16 * nt + r;
            _Float16* yp = Y + (size_t)(m0 + 4 * kq) * DH + n;
#pragma unroll
            for (int j = 0; j < 4; ++j) {
                float v = acc[nt][j];
                if (RELU) v = fmaxf(v, 0.f);
                yp[(size_t)j * DH] = (_Float16)(v * sc[j]);
            }
        }
    }
}

// ---------------- layer-3 projection: one row per lane (input pre-scaled by out_inv) ----------------
__global__ __launch_bounds__(256) void proj_out(
        const _Float16* __restrict__ X,
        const float* __restrict__ W, float* __restrict__ Z, int N) {
    __shared__ float Wl[DH * 10];
    for (int i = threadIdx.x; i < DH * 10; i += blockDim.x) Wl[i] = W[i];
    __syncthreads();

    int row = blockIdx.x * blockDim.x + threadIdx.x;
    if (row >= N) return;

    float acc[10];
#pragma unroll
    for (int o = 0; o < 10; ++o) acc[o] = 0.f;

    const half8* xp = (const half8*)(X + (size_t)row * DH);
#pragma unroll
    for (int q = 0; q < 16; ++q) {       // 16 x 8 fp16 = 128
        half8 v = xp[q];
#pragma unroll
        for (int j = 0; j < 8; ++j) {
            float x = (float)v[j];
            const float* wp = Wl + (q * 8 + j) * 10;
#pragma unroll
            for (int o = 0; o < 10; ++o)
                acc[o] += x * wp[o];
        }
    }
    float* zp = Z + (size_t)row * 10;
#pragma unroll
    for (int o = 0; o < 10; ++o) zp[o] = acc[o];
}

// ---------------- layer-3 aggregation: out[d] = in_inv[d]*sum Z[s] + b3 ----------------
__global__ void agg10(const float* __restrict__ Z, const int* __restrict__ row_off,
                      const int* __restrict__ csr_src, const float* __restrict__ in_inv,
                      const float* __restrict__ b, float* __restrict__ out, int N) {
    int r = blockIdx.x * blockDim.x + threadIdx.x;
    if (r >= N) return;
    float2 acc[5] = {};
    int start = row_off[r], end = row_off[r + 1];
    for (int e = start; e < end; ++e) {
        int s = csr_src[e];
        const float2* zp = (const float2*)(Z + (size_t)s * 10);
#pragma unroll
        for (int o = 0; o < 5; ++o) {
            float2 z = zp[o];
            acc[o].x += z.x; acc[o].y += z.y;
        }
    }
    float ii = in_inv[r];
#pragma unroll
    for (int o = 0; o < 5; ++o) {
        out[(size_t)r * 10 + 2 * o]     = acc[o].x * ii + b[2 * o];
        out[(size_t)r * 10 + 2 * o + 1] = acc[o].y * ii + b[2 * o + 1];
    }
}

extern "C" void kernel_launch(void* const* d_in, const int* in_sizes, int n_in,
                              void* d_out, int out_size, void* d_ws, size_t ws_size,
                              hipStream_t stream) {
    const float* features = (const float*)d_in[0];
    const int*   src      = (const int*)d_in[1];
    const int*   dst      = (const int*)d_in[2];
    const float* W0 = (const float*)d_in[3];
    const float* b0 = (const float*)d_in[4];
    const float* W1 = (const float*)d_in[5];
    const float* b1 = (const float*)d_in[6];
    const float* W2 = (const float*)d_in[7];
    const float* b2 = (const float*)d_in[8];
    const float* W3 = (const float*)d_in[9];
    const float* b3 = (const float*)d_in[10];
    float* out = (float*)d_out;

    char* ws = (char*)d_ws;
    int*   cnt_out = (int*)ws;                       // N
    int*   cnt_in  = cnt_out + NNODES;               // N
    int*   cursor  = cnt_in + NNODES;                // N
    int*   row_off = cursor + NNODES;                // N+1
    int*   bsums   = row_off + NNODES + 1;           // SCAN_BLOCKS
    float* out_inv = (float*)(bsums + SCAN_BLOCKS);  // N
    float* in_inv  = out_inv + NNODES;               // N
    int*   csr_src = (int*)(in_inv + NNODES);        // E
    size_t metaInts = (size_t)(6 * NNODES + 1 + SCAN_BLOCKS) + NEDGES;
    size_t off = ((metaInts * 4 + 255) / 256) * 256;
    _Float16* WThi = (_Float16*)(ws + off);  off += 3 * DH * DH * sizeof(_Float16);
    _Float16* WTlo = (_Float16*)(ws + off);  off += 3 * DH * DH * sizeof(_Float16);
    off = ((off + 255) / 256) * 256;
    _Float16* X16 = (_Float16*)(ws + off); off += (size_t)NNODES * DH * sizeof(_Float16);
    _Float16* Y16 = (_Float16*)(ws + off); off += (size_t)NNODES * DH * sizeof(_Float16);
    _Float16* F16 = (_Float16*)(ws + off); off += (size_t)NNODES * DH * sizeof(_Float16);
    float*  Z   = (float*)X16;             // layer-3: X16 dead after layer-2 gemm
    // partial count arrays alias X16/Y16 (dead until layer-0 spmm/gemm, stream-ordered)
    int* partIn  = (int*)X16;              // NSLICES*N ints = 6.4MB <= 12.8MB
    int* partOut = (int*)Y16;

    const int n4 = NNODES * DH / 4;

    // ---- CSR build + norms + W conversion + feature fp16 (once per call) ----
    count_chunked<<<NSLICES * NCHUNKS, CNT_THREADS, 0, stream>>>(src, dst, partIn, partOut);
    reduce_counts<<<(NNODES + 255) / 256, 256, 0, stream>>>(partIn, partOut, cnt_in, cnt_out, NNODES);
    scan_sums<<<SCAN_BLOCKS, SCAN_THREADS, 0, stream>>>(cnt_in, bsums, NNODES);
    scan_final<<<SCAN_BLOCKS, SCAN_THREADS, 0, stream>>>(cnt_in, bsums, cnt_out, row_off,
                                                         cursor, out_inv, in_inv, NNODES, SCAN_BLOCKS);
    scatter_kernel<<<(NEDGES + 255) / 256, 256, 0, stream>>>(src, dst, cursor, csr_src, NEDGES);
    prep_kernel<<<WCONV_BLOCKS + (n4 + 255) / 256, 256, 0, stream>>>(W0, W1, W2, WThi, WTlo,
                                                                     features, out_inv, F16, n4);

    const int spmm_blocks = (NNODES / 2 + 3) / 4;
    const int Mtiles = NNODES / 16;                 // 3125
    const int gemm_blocks = 512;

    // Layer 0
    spmm_csr<<<spmm_blocks, 256, 0, stream>>>(F16, row_off, csr_src, in_inv, X16, NNODES);
    gemm_mfma<1><<<gemm_blocks, 256, 0, stream>>>(X16, WThi, WTlo, b0, out_inv, Y16, Mtiles);
    // Layer 1
    spmm_csr<<<spmm_blocks, 256, 0, stream>>>(Y16, row_off, csr_src, in_inv, X16, NNODES);
    gemm_mfma<1><<<gemm_blocks, 256, 0, stream>>>(X16, WThi + DH * DH, WTlo + DH * DH, b1, out_inv, Y16, Mtiles);
    // Layer 2
    spmm_csr<<<spmm_blocks, 256, 0, stream>>>(Y16, row_off, csr_src, in_inv, X16, NNODES);
    gemm_mfma<1><<<gemm_blocks, 256, 0, stream>>>(X16, WThi + 2 * DH * DH, WTlo + 2 * DH * DH, b2, out_inv, Y16, Mtiles);
    // Layer 3: project to O=10 first (input pre-scaled), then aggregate 10-wide
    proj_out<<<(NNODES + 255) / 256, 256, 0, stream>>>(Y16, W3, Z, NNODES);
    agg10<<<(NNODES + 255) / 256, 256, 0, stream>>>(Z, row_off, csr_src, in_inv, b3, out, NNODES);
}